// Round 3
// baseline (2344.707 us; speedup 1.0000x reference)
//
#include <hip/hip_runtime.h>
#include <stdint.h>

// Problem constants: B=16, CIN=COUT=256, N=32, NF=17, FREQ=544, K=3
#define NFREQ 544
#define NITER 6   // Neumann iterations; ||A||~0.04 so truncation ~0.04^8

// ---- workspace layout (bytes) ----
#define WS_A_OFF   0ull                    // 544*65536 uint32 (packed bf16 complex) = 142,606,336
#define WS_XF_OFF  142606336ull            // 544*256*16 float2 = 17,825,792
#define WS_YF_OFF  160432128ull            // 544*256*16 float2 = 17,825,792
#define WS_SC_OFF  178257920ull            // scal[0]=wnorm2, scal[1]=s
#define WS_NEEDED  178257936ull

#define TWOPI_32 0.19634954084936207f      // 2*pi/32

__device__ __forceinline__ uint32_t pack_cbf(float re, float im){
  uint32_t ur = __float_as_uint(re);
  ur = (ur + 0x7fffu + ((ur >> 16) & 1u)) >> 16;          // RNE to bf16, low half
  uint32_t ui = __float_as_uint(im);
  ui = (ui + 0x7fffu + ((ui >> 16) & 1u)) & 0xffff0000u;  // RNE to bf16, high half
  return ur | ui;
}
__device__ __forceinline__ float unpack_lo(uint32_t p){ return __uint_as_float(p << 16); }
__device__ __forceinline__ float unpack_hi(uint32_t p){ return __uint_as_float(p & 0xffff0000u); }

// swizzled index into u-buffers: logical [j][c] (j=batch 0..15, c=0..255)
__device__ __forceinline__ int uidx(int j, int c){ return (j << 8) | (c ^ (((j) & 7) << 2)); }

// ---------------- K1: wnorm2 = sum_f |W_f|^2 ----------------
// W[f,a,b] = sum_{i,j in 0..2} w[a,b,i,j] * e^{i*th*(u*(i-1)+v*(j-1))}, th=2pi/32
__global__ void k_wnorm(const float* __restrict__ w, float* __restrict__ scal){
  __shared__ float cs[32], sn[32];
  __shared__ float red[256];
  const int tid = threadIdx.x;
  if (tid < 32){ float s_, c_; sincosf(TWOPI_32 * (float)tid, &s_, &c_); cs[tid]=c_; sn[tid]=s_; }
  __syncthreads();
  const float* wp = w + (blockIdx.x * 256 + tid) * 9;
  const float w00=wp[0], w01=wp[1], w02=wp[2],
              w10=wp[3], w11=wp[4], w12=wp[5],
              w20=wp[6], w21=wp[7], w22=wp[8];
  float acc = 0.f;
  for (int u = 0; u < 32; ++u){
    const float cu = cs[u], su = sn[u];
    // pd[dj] = w[0][dj+1]*conj(eu) + w[1][dj+1] + w[2][dj+1]*eu
    const float pd0r = w10 + (w00 + w20)*cu, pd0i = (w20 - w00)*su;
    const float pd1r = w11 + (w01 + w21)*cu, pd1i = (w21 - w01)*su;
    const float pd2r = w12 + (w02 + w22)*cu, pd2i = (w22 - w02)*su;
    const float sA = pd0r + pd2r, sB = pd0i - pd2i;
    const float sC = pd0i + pd2i, sD = pd2r - pd0r;
    for (int v = 0; v < 17; ++v){
      const float cv = cs[v], sv = sn[v];
      const float re = pd1r + sA*cv + sB*sv;
      const float im = pd1i + sC*cv + sD*sv;
      acc += re*re + im*im;
    }
  }
  red[tid] = acc;
  __syncthreads();
  for (int s2 = 128; s2 > 0; s2 >>= 1){
    if (tid < s2) red[tid] += red[tid + s2];
    __syncthreads();
  }
  if (tid == 0) atomicAdd(scal, red[0]);
}

// ---------------- K2: s = alpha / sqrt(wnorm2) ----------------
__global__ void k_fin(const float* __restrict__ alpha, float* __restrict__ scal){
  scal[1] = alpha[0] / sqrtf(scal[0]);
}

// ---------------- K3: A[f,a,b] = s*(W[f,a,b] - conj(W[f,b,a])), packed bf16 ----------------
__global__ void k_buildA(const float* __restrict__ w, const float* __restrict__ scal,
                         uint32_t* __restrict__ A){
  __shared__ float twr[9], twi[9];
  const int f = blockIdx.y, a = blockIdx.x, b = threadIdx.x;
  if (threadIdx.x < 9){
    const int t = threadIdx.x;
    const int u = f / 17, v = f - u*17;
    const int k = (u*(t/3 - 1) + v*(t%3 - 1)) & 31;
    float s_, c_; sincosf(TWOPI_32 * (float)k, &s_, &c_);
    twr[t] = c_; twi[t] = s_;
  }
  __syncthreads();
  const float s = scal[1];
  const float* wab = w + (a*256 + b)*9;
  const float* wba = w + (b*256 + a)*9;
  float wr=0.f, wi=0.f, xr=0.f, xi=0.f;
  #pragma unroll
  for (int t = 0; t < 9; ++t){
    const float c = twr[t], si = twi[t];
    const float p = wab[t]; wr += p*c; wi += p*si;
    const float q = wba[t]; xr += q*c; xi += q*si;
  }
  // W_ab - conj(W_ba) = (wr-xr) + i(wi+xi)
  A[((size_t)f << 16) | (a << 8) | b] = pack_cbf(s*(wr - xr), s*(wi + xi));
}

// ---------------- K4: xfft (rfft2 per 32x32 image) -> xf[f][cin][batch] ----------------
__global__ void k_xfft(const float* __restrict__ x, float2* __restrict__ xf){
  __shared__ float xs[32][32];
  __shared__ float tr[32][17], ti[32][17];
  __shared__ float cs[32], sn[32];
  const int tid = threadIdx.x;
  if (tid < 32){ float s_, c_; sincosf(TWOPI_32 * (float)tid, &s_, &c_); cs[tid]=c_; sn[tid]=s_; }
  const int bb = blockIdx.x >> 8, c = blockIdx.x & 255;
  const float* xp = x + ((size_t)blockIdx.x << 10);
  for (int i = tid; i < 1024; i += 256) xs[i >> 5][i & 31] = xp[i];
  __syncthreads();
  // stage 1: over q (rfft axis v), e^{-i th v q}
  for (int idx = tid; idx < 544; idx += 256){
    const int p = idx / 17, v = idx - p*17;
    float ar = 0.f, ai = 0.f;
    #pragma unroll 8
    for (int q = 0; q < 32; ++q){
      const int k = (v*q) & 31;
      const float xv = xs[p][q];
      ar += xv*cs[k]; ai -= xv*sn[k];
    }
    tr[p][v] = ar; ti[p][v] = ai;
  }
  __syncthreads();
  // stage 2: over p (full axis u), e^{-i th u p}
  for (int idx = tid; idx < 544; idx += 256){
    const int u = idx / 17, v = idx - u*17;
    float ar = 0.f, ai = 0.f;
    #pragma unroll 8
    for (int p = 0; p < 32; ++p){
      const int k = (u*p) & 31;
      const float cc = cs[k], ss = sn[k];
      const float pr = tr[p][v], pi = ti[p][v];
      ar += pr*cc + pi*ss;
      ai += pi*cc - pr*ss;
    }
    xf[((size_t)idx << 12) | (c << 4) | bb] = make_float2(ar, ai);
  }
}

// ---------------- K5: per-frequency Neumann solve + H GEMM ----------------
// block = one frequency; u double-buffered bf16 in LDS; A,H rows streamed from global
__global__ __launch_bounds__(512, 4)
void k_solve(const uint32_t* __restrict__ A, const float2* __restrict__ xfi,
             const float* __restrict__ Hre, const float* __restrict__ Him,
             float2* __restrict__ yfo){
  __shared__ uint32_t ubuf0[4096];
  __shared__ uint32_t ubuf1[4096];
  const int f = blockIdx.x, tid = threadIdx.x;
  const int r = tid >> 4;       // 0..31
  const int j = tid & 15;       // batch
  const float2* __restrict__ xfp = xfi + ((size_t)f << 12);
  for (int i = tid; i < 4096; i += 512){
    const float2 t = xfp[i];                       // i = c*16 + j
    ubuf0[uidx(i & 15, i >> 4)] = pack_cbf(t.x, t.y);
  }
  __syncthreads();
  const uint32_t* __restrict__ Ap = A + ((size_t)f << 16);
  uint32_t* uo = ubuf0; uint32_t* un = ubuf1;
  const int ubase = (j << 8);
  const int g = (j & 7) << 2;
  for (int pass = 0; pass <= NITER; ++pass){
    const float fac = (pass == NITER) ? 2.0f : 1.0f;
    for (int ro = 0; ro < 8; ++ro){
      const int row = (ro << 5) + r;
      const uint32_t* __restrict__ arow = Ap + (row << 8);
      float acr0=0.f, aci0=0.f, acr1=0.f, aci1=0.f;
      #pragma unroll 2
      for (int b = 0; b < 256; b += 4){
        const uint4 av = *(const uint4*)(arow + b);
        const uint4 uv = *(const uint4*)(uo + (ubase | (b ^ g)));
        float ar, ai, ur, ui;
        ar = unpack_lo(av.x); ai = unpack_hi(av.x);
        ur = unpack_lo(uv.x); ui = unpack_hi(uv.x);
        acr0 += ar*ur - ai*ui; aci0 += ar*ui + ai*ur;
        ar = unpack_lo(av.y); ai = unpack_hi(av.y);
        ur = unpack_lo(uv.y); ui = unpack_hi(uv.y);
        acr1 += ar*ur - ai*ui; aci1 += ar*ui + ai*ur;
        ar = unpack_lo(av.z); ai = unpack_hi(av.z);
        ur = unpack_lo(uv.z); ui = unpack_hi(uv.z);
        acr0 += ar*ur - ai*ui; aci0 += ar*ui + ai*ur;
        ar = unpack_lo(av.w); ai = unpack_hi(av.w);
        ur = unpack_lo(uv.w); ui = unpack_hi(uv.w);
        acr1 += ar*ur - ai*ui; aci1 += ar*ui + ai*ur;
      }
      const float2 tv = xfp[(row << 4) | j];
      un[ubase | (row ^ g)] = pack_cbf(tv.x - fac*(acr0+acr1), tv.y - fac*(aci0+aci1));
    }
    __syncthreads();
    uint32_t* tsw = uo; uo = un; un = tsw;
  }
  // yfft[f] = H[f] @ z   (z in uo)
  const float* __restrict__ Hrp = Hre + ((size_t)f << 16);
  const float* __restrict__ Hip = Him + ((size_t)f << 16);
  float2* __restrict__ yfp = yfo + ((size_t)f << 12);
  for (int ro = 0; ro < 8; ++ro){
    const int o = (ro << 5) + r;
    const float* __restrict__ hrr = Hrp + (o << 8);
    const float* __restrict__ hir = Hip + (o << 8);
    float acr0=0.f, aci0=0.f, acr1=0.f, aci1=0.f;
    #pragma unroll 2
    for (int c = 0; c < 256; c += 4){
      const float4 hv = *(const float4*)(hrr + c);
      const float4 gv = *(const float4*)(hir + c);
      const uint4 uv = *(const uint4*)(uo + (ubase | (c ^ g)));
      float zr, zi;
      zr = unpack_lo(uv.x); zi = unpack_hi(uv.x);
      acr0 += hv.x*zr - gv.x*zi; aci0 += hv.x*zi + gv.x*zr;
      zr = unpack_lo(uv.y); zi = unpack_hi(uv.y);
      acr1 += hv.y*zr - gv.y*zi; aci1 += hv.y*zi + gv.y*zr;
      zr = unpack_lo(uv.z); zi = unpack_hi(uv.z);
      acr0 += hv.z*zr - gv.z*zi; aci0 += hv.z*zi + gv.z*zr;
      zr = unpack_lo(uv.w); zi = unpack_hi(uv.w);
      acr1 += hv.w*zr - gv.w*zi; aci1 += hv.w*zi + gv.w*zr;
    }
    yfp[(o << 4) | j] = make_float2(acr0+acr1, aci0+aci1);
  }
}

// ---------------- K6: irfft2 (pocketfft c2r semantics) + bias ----------------
__global__ void k_irfft(const float2* __restrict__ yfi, const float* __restrict__ bias,
                        float* __restrict__ out){
  __shared__ float Yr[32][32], Yi[32][32];
  __shared__ float Tr[32][32], Ti[32][32];
  __shared__ float cs[32], sn[32];
  const int tid = threadIdx.x;
  if (tid < 32){ float s_, c_; sincosf(TWOPI_32 * (float)tid, &s_, &c_); cs[tid]=c_; sn[tid]=s_; }
  const int bb = blockIdx.x >> 8, co = blockIdx.x & 255;
  for (int idx = tid; idx < 544; idx += 256){
    const int u = idx / 17, v = idx - u*17;
    const float2 t = yfi[((size_t)idx << 12) + (co << 4) + bb];
    Yr[u][v] = t.x; Yi[u][v] = t.y;
  }
  __syncthreads();
  // c2r drops Im of DC/Nyquist bins along v: symmetrize columns 0 and 16 (pairs u <-> 32-u)
  if (tid < 17){
    const int u = tid, up = (32 - tid) & 31;
    #pragma unroll
    for (int vv = 0; vv < 2; ++vv){
      const int v = vv * 16;
      const float arr = Yr[u][v],  ari = Yi[u][v];
      const float brr = Yr[up][v], bri = Yi[up][v];
      Yr[u][v]  = 0.5f*(arr + brr); Yi[u][v]  = 0.5f*(ari - bri);
      Yr[up][v] = 0.5f*(brr + arr); Yi[up][v] = 0.5f*(bri - ari);
    }
  }
  // mirror-fill columns 17..31: Y[u][v] = conj(Y[(32-u)%32][32-v])
  for (int i2 = tid; i2 < 480; i2 += 256){
    const int u = i2 / 15, v = 17 + (i2 - u*15);
    const int up = (32 - u) & 31;
    Yr[u][v] =  Yr[up][32 - v];
    Yi[u][v] = -Yi[up][32 - v];
  }
  __syncthreads();
  // stage 1: over v, e^{+i th v q}
  for (int i2 = tid; i2 < 1024; i2 += 256){
    const int u = i2 >> 5, q = i2 & 31;
    float ar = 0.f, ai = 0.f;
    #pragma unroll 8
    for (int v = 0; v < 32; ++v){
      const int k = (v*q) & 31;
      const float cc = cs[k], ss = sn[k];
      const float yr = Yr[u][v], yi = Yi[u][v];
      ar += yr*cc - yi*ss;
      ai += yr*ss + yi*cc;
    }
    Tr[u][q] = ar; Ti[u][q] = ai;
  }
  __syncthreads();
  // stage 2: over u, real part of e^{+i th u p}, scale 1/1024, + bias
  const float bv = bias[co];
  for (int i2 = tid; i2 < 1024; i2 += 256){
    const int p = i2 >> 5, q = i2 & 31;
    float acc = 0.f;
    #pragma unroll 8
    for (int u = 0; u < 32; ++u){
      const int k = (u*p) & 31;
      acc += Tr[u][q]*cs[k] - Ti[u][q]*sn[k];
    }
    out[((size_t)blockIdx.x << 10) + i2] = acc * (1.0f/1024.0f) + bv;
  }
}

extern "C" void kernel_launch(void* const* d_in, const int* in_sizes, int n_in,
                              void* d_out, int out_size, void* d_ws, size_t ws_size,
                              hipStream_t stream){
  const float* x     = (const float*)d_in[0];
  const float* w     = (const float*)d_in[1];
  const float* alpha = (const float*)d_in[2];
  const float* bias  = (const float*)d_in[3];
  const float* Hre   = (const float*)d_in[4];
  const float* Him   = (const float*)d_in[5];
  float* out = (float*)d_out;

  if (ws_size < WS_NEEDED) return;  // fail loudly (output stays zero) if scratch too small

  char* ws = (char*)d_ws;
  uint32_t* A    = (uint32_t*)(ws + WS_A_OFF);
  float2*   xf   = (float2*)  (ws + WS_XF_OFF);
  float2*   yf   = (float2*)  (ws + WS_YF_OFF);
  float*    scal = (float*)   (ws + WS_SC_OFF);

  hipMemsetAsync(scal, 0, 16, stream);
  k_wnorm <<<dim3(256),        dim3(256), 0, stream>>>(w, scal);
  k_fin   <<<dim3(1),          dim3(1),   0, stream>>>(alpha, scal);
  k_buildA<<<dim3(256, NFREQ), dim3(256), 0, stream>>>(w, scal, A);
  k_xfft  <<<dim3(4096),       dim3(256), 0, stream>>>(x, xf);
  k_solve <<<dim3(NFREQ),      dim3(512), 0, stream>>>(A, xf, Hre, Him, yf);
  k_irfft <<<dim3(4096),       dim3(256), 0, stream>>>(yf, bias, out);
}

// Round 4
// 830.634 us; speedup vs baseline: 2.8228x; 2.8228x over previous
//
#include <hip/hip_runtime.h>
#include <stdint.h>

// Problem constants: B=16, CIN=COUT=256, N=32, NF=17, FREQ=544, K=3
#define NFREQ 544

// ---- workspace layout (bytes) ----
#define WS_A_OFF   0ull                    // 544*2*65536 bf16 (planar re,im) = 142,606,336
#define WS_XF_OFF  142606336ull            // 544*256*16 float2 = 17,825,792
#define WS_YF_OFF  160432128ull            // 544*256*16 float2 = 17,825,792
#define WS_SC_OFF  178257920ull            // scal[0]=wnorm2, scal[1]=s
#define WS_NEEDED  178257936ull

#define TWOPI_32 0.19634954084936207f      // 2*pi/32

using bf16x8  = __attribute__((ext_vector_type(8))) short;
using f32x4   = __attribute__((ext_vector_type(4))) float;
using short4v = __attribute__((ext_vector_type(4))) short;

__device__ __forceinline__ short bf_rne(float f){
  uint32_t u = __float_as_uint(f);
  u = (u + 0x7fffu + ((u >> 16) & 1u)) >> 16;   // RNE to bf16
  return (short)u;
}
// U-buffer swizzle (element granularity): logical [n][k] (n=batch 0..15, k=chan 0..255)
__device__ __forceinline__ int uoff(int n, int k){ return (n << 8) + (k ^ ((n & 7) << 3)); }

// ---------------- K1: wnorm2 = sum_f |W_f|^2 ----------------
__global__ void k_wnorm(const float* __restrict__ w, float* __restrict__ scal){
  __shared__ float cs[32], sn[32];
  __shared__ float red[256];
  const int tid = threadIdx.x;
  if (tid < 32){ float s_, c_; sincosf(TWOPI_32 * (float)tid, &s_, &c_); cs[tid]=c_; sn[tid]=s_; }
  __syncthreads();
  const float* wp = w + (blockIdx.x * 256 + tid) * 9;
  const float w00=wp[0], w01=wp[1], w02=wp[2],
              w10=wp[3], w11=wp[4], w12=wp[5],
              w20=wp[6], w21=wp[7], w22=wp[8];
  float acc = 0.f;
  for (int u = 0; u < 32; ++u){
    const float cu = cs[u], su = sn[u];
    const float pd0r = w10 + (w00 + w20)*cu, pd0i = (w20 - w00)*su;
    const float pd1r = w11 + (w01 + w21)*cu, pd1i = (w21 - w01)*su;
    const float pd2r = w12 + (w02 + w22)*cu, pd2i = (w22 - w02)*su;
    const float sA = pd0r + pd2r, sB = pd0i - pd2i;
    const float sC = pd0i + pd2i, sD = pd2r - pd0r;
    for (int v = 0; v < 17; ++v){
      const float cv = cs[v], sv = sn[v];
      const float re = pd1r + sA*cv + sB*sv;
      const float im = pd1i + sC*cv + sD*sv;
      acc += re*re + im*im;
    }
  }
  red[tid] = acc;
  __syncthreads();
  for (int s2 = 128; s2 > 0; s2 >>= 1){
    if (tid < s2) red[tid] += red[tid + s2];
    __syncthreads();
  }
  if (tid == 0) atomicAdd(scal, red[0]);
}

// ---------------- K2: s = alpha / sqrt(wnorm2) ----------------
__global__ void k_fin(const float* __restrict__ alpha, float* __restrict__ scal){
  scal[1] = alpha[0] / sqrtf(scal[0]);
}

// ---------------- K3: A[f][plane][a][b] = s*(W[f,a,b]-conj(W[f,b,a])), planar bf16 ----------------
__global__ void k_buildA(const float* __restrict__ w, const float* __restrict__ scal,
                         short* __restrict__ A){
  __shared__ float twr[9], twi[9];
  const int f = blockIdx.y, a = blockIdx.x, b = threadIdx.x;
  if (threadIdx.x < 9){
    const int t = threadIdx.x;
    const int u = f / 17, v = f - u*17;
    const int k = (u*(t/3 - 1) + v*(t%3 - 1)) & 31;
    float s_, c_; sincosf(TWOPI_32 * (float)k, &s_, &c_);
    twr[t] = c_; twi[t] = s_;
  }
  __syncthreads();
  const float s = scal[1];
  const float* wab = w + (a*256 + b)*9;
  const float* wba = w + (b*256 + a)*9;
  float wr=0.f, wi=0.f, xr=0.f, xi=0.f;
  #pragma unroll
  for (int t = 0; t < 9; ++t){
    const float c = twr[t], si = twi[t];
    const float p = wab[t]; wr += p*c; wi += p*si;
    const float q = wba[t]; xr += q*c; xi += q*si;
  }
  const size_t base = ((size_t)f << 17) | (a << 8) | b;
  A[base]         = bf_rne(s*(wr - xr));   // real plane
  A[base + 65536] = bf_rne(s*(wi + xi));   // imag plane
}

// ---------------- K4: xfft (rfft2 per 32x32 image) -> xf[f][cin][batch] ----------------
__global__ void k_xfft(const float* __restrict__ x, float2* __restrict__ xf){
  __shared__ float xs[32][32];
  __shared__ float tr[32][17], ti[32][17];
  __shared__ float cs[32], sn[32];
  const int tid = threadIdx.x;
  if (tid < 32){ float s_, c_; sincosf(TWOPI_32 * (float)tid, &s_, &c_); cs[tid]=c_; sn[tid]=s_; }
  const int bb = blockIdx.x >> 8, c = blockIdx.x & 255;
  const float* xp = x + ((size_t)blockIdx.x << 10);
  for (int i = tid; i < 1024; i += 256) xs[i >> 5][i & 31] = xp[i];
  __syncthreads();
  for (int idx = tid; idx < 544; idx += 256){
    const int p = idx / 17, v = idx - p*17;
    float ar = 0.f, ai = 0.f;
    #pragma unroll 8
    for (int q = 0; q < 32; ++q){
      const int k = (v*q) & 31;
      const float xv = xs[p][q];
      ar += xv*cs[k]; ai -= xv*sn[k];
    }
    tr[p][v] = ar; ti[p][v] = ai;
  }
  __syncthreads();
  for (int idx = tid; idx < 544; idx += 256){
    const int u = idx / 17, v = idx - u*17;
    float ar = 0.f, ai = 0.f;
    #pragma unroll 8
    for (int p = 0; p < 32; ++p){
      const int k = (u*p) & 31;
      const float cc = cs[k], ss = sn[k];
      const float pr = tr[p][v], pi = ti[p][v];
      ar += pr*cc + pi*ss;
      ai += pi*cc - pr*ss;
    }
    xf[((size_t)idx << 12) | (c << 4) | bb] = make_float2(ar, ai);
  }
}

// ---------------- K5: MFMA Neumann solve + H GEMM ----------------
// block = 1 freq, 512 thr = 8 waves, each wave owns 2 M-tiles (16 rows each).
// U (256 chan x 16 batch complex bf16) in LDS transposed [n][k], XOR-swizzled,
// double-buffered. A frags stream global->VGPR. H converted f32->bf16 on the fly.
// z = x - 2A(x - A(x - A(x - Ax)))  [deg-4; err <= 2||A||^5 ||x|| ~ 1e-4], then y = H z.
__global__ __launch_bounds__(512, 4)
void k_solve(const short* __restrict__ Abf, const float2* __restrict__ xfi,
             const float* __restrict__ Hre, const float* __restrict__ Him,
             float2* __restrict__ yfo){
  __shared__ __align__(16) short Ubuf[2][2][16][256];   // [buf][plane][n][k] 32 KB
  const int f = blockIdx.x, tid = threadIdx.x;
  const int lane = tid & 63, wid = tid >> 6;
  const int g = lane >> 4, n16 = lane & 15;
  const float2* __restrict__ xfp = xfi + ((size_t)f << 12);

  // stage U0 = x into buf0 (bf16, swizzled)
  {
    short* br = &Ubuf[0][0][0][0];
    short* bi = &Ubuf[0][1][0][0];
    for (int e = tid; e < 4096; e += 512){
      const float2 t = xfp[e];              // e = c*16 + b
      const int c = e >> 4, b = e & 15;
      br[uoff(b, c)] = bf_rne(t.x);
      bi[uoff(b, c)] = bf_rne(t.y);
    }
  }
  // preload x at this lane's C-fragment positions (for the x - fac*A*U update)
  float xre[2][4], xim[2][4];
  #pragma unroll
  for (int m = 0; m < 2; ++m){
    const int mt = wid*2 + m;
    #pragma unroll
    for (int i = 0; i < 4; ++i){
      const float2 t = xfp[((mt*16 + g*4 + i) << 4) | n16];
      xre[m][i] = t.x; xim[m][i] = t.y;
    }
  }
  __syncthreads();

  const short* __restrict__ Af = Abf + ((size_t)f << 17);
  int cur = 0;
  #pragma unroll 1
  for (int pass = 0; pass < 4; ++pass){
    f32x4 p1[2], p2[2], p3[2], p4[2];
    #pragma unroll
    for (int m = 0; m < 2; ++m){ p1[m] = (f32x4)0.f; p2[m] = (f32x4)0.f; p3[m] = (f32x4)0.f; p4[m] = (f32x4)0.f; }
    const short* ubr = &Ubuf[cur][0][0][0];
    const short* ubi = &Ubuf[cur][1][0][0];
    for (int kt = 0; kt < 8; ++kt){
      const int uo = uoff(n16, kt*32 + g*8);
      const bf16x8 ur = *(const bf16x8*)(ubr + uo);
      const bf16x8 ui = *(const bf16x8*)(ubi + uo);
      #pragma unroll
      for (int m = 0; m < 2; ++m){
        const int row = (wid*2 + m)*16 + n16;
        const short* ap = Af + row*256 + kt*32 + g*8;
        const bf16x8 ar = __builtin_bit_cast(bf16x8, *(const uint4*)(ap));
        const bf16x8 ai = __builtin_bit_cast(bf16x8, *(const uint4*)(ap + 65536));
        p1[m] = __builtin_amdgcn_mfma_f32_16x16x32_bf16(ar, ur, p1[m], 0, 0, 0);
        p2[m] = __builtin_amdgcn_mfma_f32_16x16x32_bf16(ai, ui, p2[m], 0, 0, 0);
        p3[m] = __builtin_amdgcn_mfma_f32_16x16x32_bf16(ar, ui, p3[m], 0, 0, 0);
        p4[m] = __builtin_amdgcn_mfma_f32_16x16x32_bf16(ai, ur, p4[m], 0, 0, 0);
      }
    }
    const float fac = (pass == 3) ? 2.0f : 1.0f;
    const int nxt = cur ^ 1;
    short* wr_ = &Ubuf[nxt][0][0][0];
    short* wi_ = &Ubuf[nxt][1][0][0];
    #pragma unroll
    for (int m = 0; m < 2; ++m){
      short4v vr, vi;
      #pragma unroll
      for (int i = 0; i < 4; ++i){
        const float Cr = p1[m][i] - p2[m][i];
        const float Ci = p3[m][i] + p4[m][i];
        vr[i] = bf_rne(xre[m][i] - fac*Cr);
        vi[i] = bf_rne(xim[m][i] - fac*Ci);
      }
      const int wo = uoff(n16, (wid*2 + m)*16 + g*4);
      *(short4v*)(wr_ + wo) = vr;
      *(short4v*)(wi_ + wo) = vi;
    }
    __syncthreads();
    cur = nxt;
  }

  // pass 5: y = H z  (H f32 -> bf16 on the fly)
  {
    f32x4 p1[2], p2[2], p3[2], p4[2];
    #pragma unroll
    for (int m = 0; m < 2; ++m){ p1[m] = (f32x4)0.f; p2[m] = (f32x4)0.f; p3[m] = (f32x4)0.f; p4[m] = (f32x4)0.f; }
    const short* ubr = &Ubuf[cur][0][0][0];
    const short* ubi = &Ubuf[cur][1][0][0];
    const float* __restrict__ hr0 = Hre + ((size_t)f << 16);
    const float* __restrict__ hi0 = Him + ((size_t)f << 16);
    for (int kt = 0; kt < 8; ++kt){
      const int uo = uoff(n16, kt*32 + g*8);
      const bf16x8 ur = *(const bf16x8*)(ubr + uo);
      const bf16x8 ui = *(const bf16x8*)(ubi + uo);
      #pragma unroll
      for (int m = 0; m < 2; ++m){
        const int row = (wid*2 + m)*16 + n16;
        const float* hp = hr0 + row*256 + kt*32 + g*8;
        const float* gp = hi0 + row*256 + kt*32 + g*8;
        const float4 h0 = *(const float4*)(hp), h1 = *(const float4*)(hp + 4);
        const float4 g0 = *(const float4*)(gp), g1 = *(const float4*)(gp + 4);
        bf16x8 hrf, hif;
        hrf[0]=bf_rne(h0.x); hrf[1]=bf_rne(h0.y); hrf[2]=bf_rne(h0.z); hrf[3]=bf_rne(h0.w);
        hrf[4]=bf_rne(h1.x); hrf[5]=bf_rne(h1.y); hrf[6]=bf_rne(h1.z); hrf[7]=bf_rne(h1.w);
        hif[0]=bf_rne(g0.x); hif[1]=bf_rne(g0.y); hif[2]=bf_rne(g0.z); hif[3]=bf_rne(g0.w);
        hif[4]=bf_rne(g1.x); hif[5]=bf_rne(g1.y); hif[6]=bf_rne(g1.z); hif[7]=bf_rne(g1.w);
        p1[m] = __builtin_amdgcn_mfma_f32_16x16x32_bf16(hrf, ur, p1[m], 0, 0, 0);
        p2[m] = __builtin_amdgcn_mfma_f32_16x16x32_bf16(hif, ui, p2[m], 0, 0, 0);
        p3[m] = __builtin_amdgcn_mfma_f32_16x16x32_bf16(hrf, ui, p3[m], 0, 0, 0);
        p4[m] = __builtin_amdgcn_mfma_f32_16x16x32_bf16(hif, ur, p4[m], 0, 0, 0);
      }
    }
    float2* __restrict__ yfp = yfo + ((size_t)f << 12);
    #pragma unroll
    for (int m = 0; m < 2; ++m){
      #pragma unroll
      for (int i = 0; i < 4; ++i){
        const int o = (wid*2 + m)*16 + g*4 + i;
        yfp[(o << 4) | n16] = make_float2(p1[m][i] - p2[m][i], p3[m][i] + p4[m][i]);
      }
    }
  }
}

// ---------------- K6: irfft2 (pocketfft c2r semantics) + bias ----------------
__global__ void k_irfft(const float2* __restrict__ yfi, const float* __restrict__ bias,
                        float* __restrict__ out){
  __shared__ float Yr[32][32], Yi[32][32];
  __shared__ float Tr[32][32], Ti[32][32];
  __shared__ float cs[32], sn[32];
  const int tid = threadIdx.x;
  if (tid < 32){ float s_, c_; sincosf(TWOPI_32 * (float)tid, &s_, &c_); cs[tid]=c_; sn[tid]=s_; }
  const int bb = blockIdx.x >> 8, co = blockIdx.x & 255;
  for (int idx = tid; idx < 544; idx += 256){
    const int u = idx / 17, v = idx - u*17;
    const float2 t = yfi[((size_t)idx << 12) + (co << 4) + bb];
    Yr[u][v] = t.x; Yi[u][v] = t.y;
  }
  __syncthreads();
  if (tid < 17){
    const int u = tid, up = (32 - tid) & 31;
    #pragma unroll
    for (int vv = 0; vv < 2; ++vv){
      const int v = vv * 16;
      const float arr = Yr[u][v],  ari = Yi[u][v];
      const float brr = Yr[up][v], bri = Yi[up][v];
      Yr[u][v]  = 0.5f*(arr + brr); Yi[u][v]  = 0.5f*(ari - bri);
      Yr[up][v] = 0.5f*(brr + arr); Yi[up][v] = 0.5f*(bri - ari);
    }
  }
  for (int i2 = tid; i2 < 480; i2 += 256){
    const int u = i2 / 15, v = 17 + (i2 - u*15);
    const int up = (32 - u) & 31;
    Yr[u][v] =  Yr[up][32 - v];
    Yi[u][v] = -Yi[up][32 - v];
  }
  __syncthreads();
  for (int i2 = tid; i2 < 1024; i2 += 256){
    const int u = i2 >> 5, q = i2 & 31;
    float ar = 0.f, ai = 0.f;
    #pragma unroll 8
    for (int v = 0; v < 32; ++v){
      const int k = (v*q) & 31;
      const float cc = cs[k], ss = sn[k];
      const float yr = Yr[u][v], yi = Yi[u][v];
      ar += yr*cc - yi*ss;
      ai += yr*ss + yi*cc;
    }
    Tr[u][q] = ar; Ti[u][q] = ai;
  }
  __syncthreads();
  const float bv = bias[co];
  for (int i2 = tid; i2 < 1024; i2 += 256){
    const int p = i2 >> 5, q = i2 & 31;
    float acc = 0.f;
    #pragma unroll 8
    for (int u = 0; u < 32; ++u){
      const int k = (u*p) & 31;
      acc += Tr[u][q]*cs[k] - Ti[u][q]*sn[k];
    }
    out[((size_t)blockIdx.x << 10) + i2] = acc * (1.0f/1024.0f) + bv;
  }
}

extern "C" void kernel_launch(void* const* d_in, const int* in_sizes, int n_in,
                              void* d_out, int out_size, void* d_ws, size_t ws_size,
                              hipStream_t stream){
  const float* x     = (const float*)d_in[0];
  const float* w     = (const float*)d_in[1];
  const float* alpha = (const float*)d_in[2];
  const float* bias  = (const float*)d_in[3];
  const float* Hre   = (const float*)d_in[4];
  const float* Him   = (const float*)d_in[5];
  float* out = (float*)d_out;

  if (ws_size < WS_NEEDED) return;

  char* ws = (char*)d_ws;
  short*  A    = (short*) (ws + WS_A_OFF);
  float2* xf   = (float2*)(ws + WS_XF_OFF);
  float2* yf   = (float2*)(ws + WS_YF_OFF);
  float*  scal = (float*) (ws + WS_SC_OFF);

  hipMemsetAsync(scal, 0, 16, stream);
  k_wnorm <<<dim3(256),        dim3(256), 0, stream>>>(w, scal);
  k_fin   <<<dim3(1),          dim3(1),   0, stream>>>(alpha, scal);
  k_buildA<<<dim3(256, NFREQ), dim3(256), 0, stream>>>(w, scal, A);
  k_xfft  <<<dim3(4096),       dim3(256), 0, stream>>>(x, xf);
  k_solve <<<dim3(NFREQ),      dim3(512), 0, stream>>>(A, xf, Hre, Him, yf);
  k_irfft <<<dim3(4096),       dim3(256), 0, stream>>>(yf, bias, out);
}